// Round 2
// baseline (435.045 us; speedup 1.0000x reference)
//
#include <hip/hip_runtime.h>
#include <hip/hip_bf16.h>

#define DD 1024
#define HH 16
#define BB 2
#define TT 2048
#define DHH 64
#define MM (BB * TT)   // 4096 rows

typedef __attribute__((ext_vector_type(8))) short bfrag;
typedef __attribute__((ext_vector_type(4))) float ffrag;

__device__ __forceinline__ unsigned short f2bf(float f) {
    __hip_bfloat16 h = __float2bfloat16(f);
    return *reinterpret_cast<unsigned short*>(&h);
}

// Load 8 contiguous elements as bf16 into out8. Specialized for fp32 (convert)
// and bf16-as-ushort (direct 16B copy).
__device__ __forceinline__ void load8_to_bf16(const float* __restrict__ p, unsigned short* out8) {
    float4 a = *(const float4*)p;
    float4 b = *(const float4*)(p + 4);
    out8[0] = f2bf(a.x); out8[1] = f2bf(a.y); out8[2] = f2bf(a.z); out8[3] = f2bf(a.w);
    out8[4] = f2bf(b.x); out8[5] = f2bf(b.y); out8[6] = f2bf(b.z); out8[7] = f2bf(b.w);
}
__device__ __forceinline__ void load8_to_bf16(const unsigned short* __restrict__ p, unsigned short* out8) {
    uint4 v = *(const uint4*)p;
    *(uint4*)out8 = v;
}

// Computes 64x64 tile of C = X @ W, X:[MM,1024] row-major, W:[1024,1024] row-major.
// acc[s][r]: row m0 + w*16 + (lane/16)*4 + r, col n0 + s*16 + (lane%16). fp32.
template <typename TA, typename TB>
__device__ __forceinline__ void gemm64x64(
    const TA* __restrict__ X, const TB* __restrict__ W,
    int m0, int n0,
    unsigned short (*As)[72], unsigned short (*Bs)[72],
    ffrag acc[4])
{
    const int t  = threadIdx.x;
    const int l  = t & 63, w = t >> 6;
    const int lm = l & 15, lq = l >> 4;
    const int r0 = t >> 3, c0 = (t & 7) * 8;
#pragma unroll
    for (int s = 0; s < 4; ++s) acc[s] = (ffrag){0.f, 0.f, 0.f, 0.f};

    for (int k0 = 0; k0 < DD; k0 += 64) {
#pragma unroll
        for (int g = 0; g < 2; ++g) {
            int row = r0 + g * 32;
            // A tile: rows m0+row, cols k0+c0..+8
            __align__(16) unsigned short a8[8];
            load8_to_bf16(&X[(size_t)(m0 + row) * DD + k0 + c0], a8);
            *(uint4*)&As[row][c0] = *(const uint4*)a8;
            // B tile: read row-major, scatter transposed Bs[n][k]
            __align__(16) unsigned short b8[8];
            load8_to_bf16(&W[(size_t)(k0 + row) * DD + n0 + c0], b8);
#pragma unroll
            for (int i = 0; i < 8; ++i) Bs[c0 + i][row] = b8[i];
        }
        __syncthreads();
#pragma unroll
        for (int kc = 0; kc < 2; ++kc) {
            bfrag a = *(const bfrag*)&As[w * 16 + lm][kc * 32 + lq * 8];
#pragma unroll
            for (int s = 0; s < 4; ++s) {
                bfrag b = *(const bfrag*)&Bs[s * 16 + lm][kc * 32 + lq * 8];
                acc[s] = __builtin_amdgcn_mfma_f32_16x16x32_bf16(a, b, acc[s], 0, 0, 0);
            }
        }
        __syncthreads();
    }
}

// blockIdx.x = n-tile (== head), blockIdx.y = m-tile, blockIdx.z = {Q,K,V}
__global__ __launch_bounds__(256) void qkv_rope_kernel(
    const float* __restrict__ x,
    const float* __restrict__ wq, const float* __restrict__ bq,
    const float* __restrict__ wk, const float* __restrict__ bk,
    const float* __restrict__ wv, const float* __restrict__ bv,
    unsigned short* __restrict__ Qh, unsigned short* __restrict__ Kh,
    unsigned short* __restrict__ Vh)
{
    __shared__ __align__(16) unsigned short As[64][72];
    __shared__ __align__(16) unsigned short Bs[64][72];

    const int which = blockIdx.z;
    const float* W    = (which == 0) ? wq : (which == 1) ? wk : wv;
    const float* bias = (which == 0) ? bq : (which == 1) ? bk : bv;
    unsigned short* Out = (which == 0) ? Qh : (which == 1) ? Kh : Vh;

    const int n0 = blockIdx.x * 64, m0 = blockIdx.y * 64;
    ffrag acc[4];
    gemm64x64(x, W, m0, n0, As, Bs, acc);

    const int t  = threadIdx.x;
    const int l  = t & 63, w = t >> 6;
    const int lm = l & 15, lq = l >> 4;
    const int h  = blockIdx.x;   // n-tile of 64 == one head

    float bv4[4];
#pragma unroll
    for (int s = 0; s < 4; ++s) bv4[s] = bias[n0 + s * 16 + lm];

#pragma unroll
    for (int r = 0; r < 4; ++r) {
        const int row  = m0 + w * 16 + lq * 4 + r;   // global row in [0,4096)
        const int b    = row >> 11;                  // /2048
        const int tpos = row & 2047;
#pragma unroll
        for (int s = 0; s < 4; ++s) {
            const int j = s * 16 + lm;               // dh index in [0,64)
            float val = acc[s][r] + bv4[s];
            float outv;
            if (which < 2) {
                // RoPE: sin/cos repeat-2, rotate_half = concat(-u[32:], u[:32])
                float pair = acc[s ^ 2][r] + bv4[s ^ 2];
                float rh   = (j < 32) ? -pair : pair;
                int   i    = j >> 1;
                // inv = 10000^(-i/32)
                float inv  = __expf(-(float)i * (9.210340371976184f / 32.0f));
                float ang  = (float)tpos * inv;
                float sv, cv;
                sincosf(ang, &sv, &cv);
                outv = val * cv + rh * sv;
            } else {
                outv = val;
            }
            Out[(((size_t)b * HH + h) * TT + tpos) * DHH + j] = f2bf(outv);
        }
    }
}

// Flash attention, causal. blockIdx.x = q-tile (64 rows), blockIdx.y = b*H+h.
__global__ __launch_bounds__(256) void attn_kernel(
    const unsigned short* __restrict__ Qh, const unsigned short* __restrict__ Kh,
    const unsigned short* __restrict__ Vh, unsigned short* __restrict__ attn_out)
{
    __shared__ __align__(16) unsigned short Ks[64][72];  // [kcol][dh]
    __shared__ __align__(16) unsigned short Vt[64][72];  // [dh][kcol]
    __shared__ __align__(16) unsigned short Pl[4][16][72];

    const int qt = blockIdx.x;
    const int bh = blockIdx.y;
    const int t  = threadIdx.x;
    const int l  = t & 63, w = t >> 6;
    const int lm = l & 15, lq = l >> 4;
    const int q0 = qt * 64, wm0 = q0 + w * 16;
    const int r0 = t >> 3, c0 = (t & 7) * 8;

    const unsigned short* Qb = Qh + (size_t)bh * TT * DHH;
    const unsigned short* Kb = Kh + (size_t)bh * TT * DHH;
    const unsigned short* Vb = Vh + (size_t)bh * TT * DHH;

    // Q fragments held in registers across the whole K loop
    bfrag qf[2];
#pragma unroll
    for (int kc = 0; kc < 2; ++kc)
        qf[kc] = *(const bfrag*)&Qb[(size_t)(wm0 + lm) * DHH + kc * 32 + lq * 8];

    ffrag o[4];
#pragma unroll
    for (int s = 0; s < 4; ++s) o[s] = (ffrag){0.f, 0.f, 0.f, 0.f};
    float mrow[4], lrow[4];
#pragma unroll
    for (int r = 0; r < 4; ++r) { mrow[r] = -1e30f; lrow[r] = 0.f; }

    const int nkt = qt + 1;   // causal: only tiles with k0 <= q0
    for (int kt = 0; kt < nkt; ++kt) {
        const int k0 = kt * 64;
#pragma unroll
        for (int g = 0; g < 2; ++g) {
            int row = r0 + g * 32;
            uint4 kv = *(const uint4*)&Kb[(size_t)(k0 + row) * DHH + c0];
            *(uint4*)&Ks[row][c0] = kv;
            uint4 vv = *(const uint4*)&Vb[(size_t)(k0 + row) * DHH + c0];
            const unsigned short* vs = (const unsigned short*)&vv;
#pragma unroll
            for (int i = 0; i < 8; ++i) Vt[c0 + i][row] = vs[i];
        }
        __syncthreads();

        {
            float sv[4][4];
#pragma unroll
            for (int s = 0; s < 4; ++s) {
                ffrag sa = (ffrag){0.f, 0.f, 0.f, 0.f};
#pragma unroll
                for (int kc = 0; kc < 2; ++kc) {
                    bfrag b = *(const bfrag*)&Ks[s * 16 + lm][kc * 32 + lq * 8];
                    sa = __builtin_amdgcn_mfma_f32_16x16x32_bf16(qf[kc], b, sa, 0, 0, 0);
                }
#pragma unroll
                for (int r = 0; r < 4; ++r) {
                    int col  = k0 + s * 16 + lm;
                    int rowg = wm0 + lq * 4 + r;
                    float v  = sa[r] * 0.125f;                 // 1/sqrt(64)
                    sv[s][r] = (col <= rowg) ? v : -1e30f;     // causal mask
                }
            }
            float newm[4], alpha[4], psum[4];
#pragma unroll
            for (int r = 0; r < 4; ++r) {
                float mx = fmaxf(fmaxf(sv[0][r], sv[1][r]), fmaxf(sv[2][r], sv[3][r]));
#pragma unroll
                for (int off = 8; off >= 1; off >>= 1)
                    mx = fmaxf(mx, __shfl_xor(mx, off, 64));
                newm[r]  = fmaxf(mrow[r], mx);
                alpha[r] = __expf(mrow[r] - newm[r]);
                psum[r]  = 0.f;
            }
#pragma unroll
            for (int s = 0; s < 4; ++s)
#pragma unroll
                for (int r = 0; r < 4; ++r) {
                    float p = __expf(sv[s][r] - newm[r]);
                    sv[s][r] = p;
                    psum[r] += p;
                }
#pragma unroll
            for (int r = 0; r < 4; ++r) {
#pragma unroll
                for (int off = 8; off >= 1; off >>= 1)
                    psum[r] += __shfl_xor(psum[r], off, 64);
                lrow[r] = lrow[r] * alpha[r] + psum[r];
                mrow[r] = newm[r];
            }
            // P: C-layout -> A-layout via per-wave LDS round trip
#pragma unroll
            for (int s = 0; s < 4; ++s)
#pragma unroll
                for (int r = 0; r < 4; ++r)
                    Pl[w][lq * 4 + r][s * 16 + lm] = f2bf(sv[s][r]);
            asm volatile("s_waitcnt lgkmcnt(0)" ::: "memory");
#pragma unroll
            for (int s = 0; s < 4; ++s)
#pragma unroll
                for (int r = 0; r < 4; ++r) o[s][r] *= alpha[r];
#pragma unroll
            for (int s = 0; s < 4; ++s) {
#pragma unroll
                for (int kc = 0; kc < 2; ++kc) {
                    bfrag a = *(const bfrag*)&Pl[w][lm][kc * 32 + lq * 8];
                    bfrag b = *(const bfrag*)&Vt[s * 16 + lm][kc * 32 + lq * 8];
                    o[s] = __builtin_amdgcn_mfma_f32_16x16x32_bf16(a, b, o[s], 0, 0, 0);
                }
            }
        }
        __syncthreads();
    }

    // epilogue: normalize, store to [B, T, H, DH] (== [B,T,D] concat-heads)
    const int b = bh >> 4, h = bh & 15;
#pragma unroll
    for (int r = 0; r < 4; ++r) {
        const int trow = wm0 + lq * 4 + r;
        const float linv = 1.0f / lrow[r];
#pragma unroll
        for (int s = 0; s < 4; ++s) {
            float ov = o[s][r] * linv;
            attn_out[(((size_t)b * TT + trow) * HH + h) * DHH + s * 16 + lm] = f2bf(ov);
        }
    }
}

__global__ __launch_bounds__(256) void oproj_kernel(
    const unsigned short* __restrict__ attn, const float* __restrict__ wo,
    const float* __restrict__ bo, float* __restrict__ out)
{
    __shared__ __align__(16) unsigned short As[64][72];
    __shared__ __align__(16) unsigned short Bs[64][72];
    const int n0 = blockIdx.x * 64, m0 = blockIdx.y * 64;
    ffrag acc[4];
    gemm64x64(attn, wo, m0, n0, As, Bs, acc);

    const int t  = threadIdx.x;
    const int l  = t & 63, w = t >> 6;
    const int lm = l & 15, lq = l >> 4;
#pragma unroll
    for (int s = 0; s < 4; ++s) {
        const float bb = bo[n0 + s * 16 + lm];
#pragma unroll
        for (int r = 0; r < 4; ++r) {
            const int row = m0 + w * 16 + lq * 4 + r;
            out[(size_t)row * DD + n0 + s * 16 + lm] = acc[s][r] + bb;
        }
    }
}

extern "C" void kernel_launch(void* const* d_in, const int* in_sizes, int n_in,
                              void* d_out, int out_size, void* d_ws, size_t ws_size,
                              hipStream_t stream) {
    const float* x  = (const float*)d_in[0];
    // d_in[1] = causal mask (deterministic triu) — not read
    const float* wq = (const float*)d_in[2];
    const float* bq = (const float*)d_in[3];
    const float* wk = (const float*)d_in[4];
    const float* bk = (const float*)d_in[5];
    const float* wv = (const float*)d_in[6];
    const float* bv = (const float*)d_in[7];
    const float* wo = (const float*)d_in[8];
    const float* bo = (const float*)d_in[9];

    const size_t perT = (size_t)BB * HH * TT * DHH;   // 4,194,304 elems
    unsigned short* Qh   = (unsigned short*)d_ws;
    unsigned short* Kh   = Qh + perT;
    unsigned short* Vh   = Kh + perT;
    unsigned short* attn = Vh + perT;

    qkv_rope_kernel<<<dim3(16, 64, 3), 256, 0, stream>>>(x, wq, bq, wk, bk, wv, bv, Qh, Kh, Vh);
    attn_kernel<<<dim3(32, 32), 256, 0, stream>>>(Qh, Kh, Vh, attn);
    oproj_kernel<<<dim3(16, 64), 256, 0, stream>>>(attn, wo, bo, (float*)d_out);
}

// Round 3
// 327.765 us; speedup vs baseline: 1.3273x; 1.3273x over previous
//
#include <hip/hip_runtime.h>
#include <hip/hip_bf16.h>

#define DD 1024
#define HH 16
#define BB 2
#define TT 2048
#define DHH 64
#define MM (BB * TT)   // 4096 rows

typedef __attribute__((ext_vector_type(8))) short bfrag;
typedef __attribute__((ext_vector_type(4))) float ffrag;

__device__ __forceinline__ unsigned short f2bf(float f) {
    __hip_bfloat16 h = __float2bfloat16(f);
    return *reinterpret_cast<unsigned short*>(&h);
}

// ---------- prepass: x fp32 -> bf16 ----------
__global__ __launch_bounds__(256) void conv_x_kernel(
    const float* __restrict__ x, unsigned short* __restrict__ xb)
{
    int i = blockIdx.x * 256 + threadIdx.x;      // float4 index
    float4 v = ((const float4*)x)[i];
    ushort4 o;
    o.x = f2bf(v.x); o.y = f2bf(v.y); o.z = f2bf(v.z); o.w = f2bf(v.w);
    ((ushort4*)xb)[i] = o;
}

// ---------- prepass: W[k][n] fp32 -> Wt[n][k] bf16 ----------
__global__ __launch_bounds__(256) void transpose_w_kernel(
    const float* __restrict__ wq, const float* __restrict__ wk,
    const float* __restrict__ wv, const float* __restrict__ wo,
    unsigned short* __restrict__ oq, unsigned short* __restrict__ ok,
    unsigned short* __restrict__ ov, unsigned short* __restrict__ oo)
{
    __shared__ float T[64][65];
    const int z = blockIdx.z;
    const float* W   = (z == 0) ? wq : (z == 1) ? wk : (z == 2) ? wv : wo;
    unsigned short* O = (z == 0) ? oq : (z == 1) ? ok : (z == 2) ? ov : oo;
    const int n0 = blockIdx.x * 64, k0 = blockIdx.y * 64;
    const int t = threadIdx.x;
#pragma unroll
    for (int g = 0; g < 16; ++g) {
        int idx = g * 256 + t;
        int r = idx >> 6, c = idx & 63;          // r = k-local, c = n-local
        T[c][r] = W[(size_t)(k0 + r) * DD + n0 + c];
    }
    __syncthreads();
#pragma unroll
    for (int g = 0; g < 16; ++g) {
        int idx = g * 256 + t;
        int r = idx >> 6, c = idx & 63;          // r = n-local, c = k-local
        O[(size_t)(n0 + r) * DD + k0 + c] = f2bf(T[r][c]);
    }
}

// 64x64 tile of C = X @ Wt^T. X:[MM,1024] bf16 row-major, Wt:[1024 n][1024 k]
// bf16 row-major (pre-transposed weight). All LDS staging is contiguous b128.
// acc[s][r]: row m0 + w*16 + (lane/16)*4 + r, col n0 + s*16 + (lane%16).
__device__ __forceinline__ void gemm64x64(
    const unsigned short* __restrict__ X, const unsigned short* __restrict__ Wt,
    int m0, int n0,
    unsigned short (*As)[72], unsigned short (*Bs)[72],
    ffrag acc[4])
{
    const int t  = threadIdx.x;
    const int l  = t & 63, w = t >> 6;
    const int lm = l & 15, lq = l >> 4;
    const int r0 = t >> 3, c0 = (t & 7) * 8;
#pragma unroll
    for (int s = 0; s < 4; ++s) acc[s] = (ffrag){0.f, 0.f, 0.f, 0.f};

    for (int k0 = 0; k0 < DD; k0 += 64) {
#pragma unroll
        for (int g = 0; g < 2; ++g) {
            int row = r0 + g * 32;
            *(uint4*)&As[row][c0] = *(const uint4*)&X [(size_t)(m0 + row) * DD + k0 + c0];
            *(uint4*)&Bs[row][c0] = *(const uint4*)&Wt[(size_t)(n0 + row) * DD + k0 + c0];
        }
        __syncthreads();
#pragma unroll
        for (int kc = 0; kc < 2; ++kc) {
            bfrag a = *(const bfrag*)&As[w * 16 + lm][kc * 32 + lq * 8];
#pragma unroll
            for (int s = 0; s < 4; ++s) {
                bfrag b = *(const bfrag*)&Bs[s * 16 + lm][kc * 32 + lq * 8];
                acc[s] = __builtin_amdgcn_mfma_f32_16x16x32_bf16(a, b, acc[s], 0, 0, 0);
            }
        }
        __syncthreads();
    }
}

// blockIdx.x = n-tile (== head), blockIdx.y = m-tile, blockIdx.z = {Q,K,V}
// Q,K stored [B*H, T, DH]; V stored TRANSPOSED [B*H, DH, T].
__global__ __launch_bounds__(256) void qkv_rope_kernel(
    const unsigned short* __restrict__ xb,
    const unsigned short* __restrict__ wtq, const float* __restrict__ bq,
    const unsigned short* __restrict__ wtk, const float* __restrict__ bk,
    const unsigned short* __restrict__ wtv, const float* __restrict__ bv,
    unsigned short* __restrict__ Qh, unsigned short* __restrict__ Kh,
    unsigned short* __restrict__ Vh)
{
    __shared__ __align__(16) unsigned short As[64][72];
    __shared__ __align__(16) unsigned short Bs[64][72];

    const int which = blockIdx.z;
    const unsigned short* Wt = (which == 0) ? wtq : (which == 1) ? wtk : wtv;
    const float* bias        = (which == 0) ? bq  : (which == 1) ? bk  : bv;
    unsigned short* Out      = (which == 0) ? Qh  : (which == 1) ? Kh  : Vh;

    const int n0 = blockIdx.x * 64, m0 = blockIdx.y * 64;
    ffrag acc[4];
    gemm64x64(xb, Wt, m0, n0, As, Bs, acc);

    const int t  = threadIdx.x;
    const int l  = t & 63, w = t >> 6;
    const int lm = l & 15, lq = l >> 4;
    const int h  = blockIdx.x;   // n-tile of 64 == one head

    float bv4[4];
#pragma unroll
    for (int s = 0; s < 4; ++s) bv4[s] = bias[n0 + s * 16 + lm];

#pragma unroll
    for (int r = 0; r < 4; ++r) {
        const int row  = m0 + w * 16 + lq * 4 + r;   // global row in [0,4096)
        const int b    = row >> 11;                  // /2048
        const int tpos = row & 2047;
        const int bh   = b * HH + h;
#pragma unroll
        for (int s = 0; s < 4; ++s) {
            const int j = s * 16 + lm;               // dh index in [0,64)
            float val = acc[s][r] + bv4[s];
            if (which < 2) {
                // RoPE: sin/cos repeat-2, rotate_half = concat(-u[32:], u[:32])
                float pair = acc[s ^ 2][r] + bv4[s ^ 2];
                float rh   = (j < 32) ? -pair : pair;
                int   i    = j >> 1;
                float inv  = __expf(-(float)i * (9.210340371976184f / 32.0f));
                float ang  = (float)tpos * inv;
                float sv, cv;
                sincosf(ang, &sv, &cv);
                float outv = val * cv + rh * sv;
                Out[((size_t)bh * TT + tpos) * DHH + j] = f2bf(outv);
            } else {
                // V: transposed store [bh][dh][t]
                Out[((size_t)bh * DHH + j) * TT + tpos] = f2bf(val);
            }
        }
    }
}

// Flash attention, causal. blockIdx.x -> q-tile (reversed), blockIdx.y = b*H+h.
__global__ __launch_bounds__(256) void attn_kernel(
    const unsigned short* __restrict__ Qh, const unsigned short* __restrict__ Kh,
    const unsigned short* __restrict__ Vh, unsigned short* __restrict__ attn_out)
{
    __shared__ __align__(16) unsigned short Ks[64][72];  // [kcol][dh]
    __shared__ __align__(16) unsigned short Vt[64][72];  // [dh][kcol]
    __shared__ __align__(16) unsigned short Pl[4][16][72];

    const int qt = (gridDim.x - 1) - blockIdx.x;   // longest blocks first
    const int bh = blockIdx.y;
    const int t  = threadIdx.x;
    const int l  = t & 63, w = t >> 6;
    const int lm = l & 15, lq = l >> 4;
    const int q0 = qt * 64, wm0 = q0 + w * 16;
    const int r0 = t >> 3, c0 = (t & 7) * 8;
    const float SCALE = 0.125f * 1.4426950408889634f;   // 1/sqrt(64) * log2(e)

    const unsigned short* Qb = Qh + (size_t)bh * TT * DHH;
    const unsigned short* Kb = Kh + (size_t)bh * TT * DHH;
    const unsigned short* Vb = Vh + (size_t)bh * DHH * TT;   // transposed

    bfrag qf[2];
#pragma unroll
    for (int kc = 0; kc < 2; ++kc)
        qf[kc] = *(const bfrag*)&Qb[(size_t)(wm0 + lm) * DHH + kc * 32 + lq * 8];

    ffrag o[4];
#pragma unroll
    for (int s = 0; s < 4; ++s) o[s] = (ffrag){0.f, 0.f, 0.f, 0.f};
    float mrow[4], lrow[4];
#pragma unroll
    for (int r = 0; r < 4; ++r) { mrow[r] = -1e30f; lrow[r] = 0.f; }

    const int nkt = qt + 1;
    for (int kt = 0; kt < nkt; ++kt) {
        const int k0 = kt * 64;
#pragma unroll
        for (int g = 0; g < 2; ++g) {
            int row = r0 + g * 32;
            *(uint4*)&Ks[row][c0] = *(const uint4*)&Kb[(size_t)(k0 + row) * DHH + c0];
            *(uint4*)&Vt[row][c0] = *(const uint4*)&Vb[(size_t)row * TT + k0 + c0];
        }
        __syncthreads();

        float sv[4][4];
#pragma unroll
        for (int s = 0; s < 4; ++s) {
            ffrag sa = (ffrag){0.f, 0.f, 0.f, 0.f};
#pragma unroll
            for (int kc = 0; kc < 2; ++kc) {
                bfrag b = *(const bfrag*)&Ks[s * 16 + lm][kc * 32 + lq * 8];
                sa = __builtin_amdgcn_mfma_f32_16x16x32_bf16(qf[kc], b, sa, 0, 0, 0);
            }
#pragma unroll
            for (int r = 0; r < 4; ++r) {
                int col  = k0 + s * 16 + lm;
                int rowg = wm0 + lq * 4 + r;
                float v  = sa[r] * SCALE;                  // log2-domain score
                sv[s][r] = (col <= rowg) ? v : -1e30f;
            }
        }
        float newm[4], alpha[4], psum[4];
#pragma unroll
        for (int r = 0; r < 4; ++r) {
            float mx = fmaxf(fmaxf(sv[0][r], sv[1][r]), fmaxf(sv[2][r], sv[3][r]));
#pragma unroll
            for (int off = 8; off >= 1; off >>= 1)
                mx = fmaxf(mx, __shfl_xor(mx, off, 64));
            newm[r]  = fmaxf(mrow[r], mx);
            alpha[r] = exp2f(mrow[r] - newm[r]);
            psum[r]  = 0.f;
        }
#pragma unroll
        for (int s = 0; s < 4; ++s)
#pragma unroll
            for (int r = 0; r < 4; ++r) {
                float p = exp2f(sv[s][r] - newm[r]);
                sv[s][r] = p;
                psum[r] += p;
            }
#pragma unroll
        for (int r = 0; r < 4; ++r) {
#pragma unroll
            for (int off = 8; off >= 1; off >>= 1)
                psum[r] += __shfl_xor(psum[r], off, 64);
            lrow[r] = lrow[r] * alpha[r] + psum[r];
            mrow[r] = newm[r];
        }
        // P: C-layout -> A-layout via per-wave LDS round trip, XOR-swizzled
        // s-block so the 16 scalar writes spread over all 32 banks.
#pragma unroll
        for (int s = 0; s < 4; ++s) {
            const int ssw = (s ^ ((4 - lq) & 3)) * 16 + lm;
#pragma unroll
            for (int r = 0; r < 4; ++r)
                Pl[w][lq * 4 + r][ssw] = f2bf(sv[s][r]);
        }
        asm volatile("s_waitcnt lgkmcnt(0)" ::: "memory");
#pragma unroll
        for (int s = 0; s < 4; ++s)
#pragma unroll
            for (int r = 0; r < 4; ++r) o[s][r] *= alpha[r];
        const int gsw = (4 - (lm >> 2)) & 3;   // writer-lq of row lm
#pragma unroll
        for (int kc = 0; kc < 2; ++kc) {
            const int scol = ((kc * 2 + (lq >> 1)) ^ gsw) * 16 + (lq & 1) * 8;
            bfrag a = *(const bfrag*)&Pl[w][lm][scol];
#pragma unroll
            for (int s = 0; s < 4; ++s) {
                bfrag b = *(const bfrag*)&Vt[s * 16 + lm][kc * 32 + lq * 8];
                o[s] = __builtin_amdgcn_mfma_f32_16x16x32_bf16(a, b, o[s], 0, 0, 0);
            }
        }
        __syncthreads();
    }

    // epilogue: normalize, store to [B, T, H, DH] (== [B,T,D] concat-heads)
    const int b = bh >> 4, h = bh & 15;
#pragma unroll
    for (int r = 0; r < 4; ++r) {
        const int trow = wm0 + lq * 4 + r;
        const float linv = 1.0f / lrow[r];
#pragma unroll
        for (int s = 0; s < 4; ++s) {
            float ov = o[s][r] * linv;
            attn_out[(((size_t)b * TT + trow) * HH + h) * DHH + s * 16 + lm] = f2bf(ov);
        }
    }
}

__global__ __launch_bounds__(256) void oproj_kernel(
    const unsigned short* __restrict__ attn, const unsigned short* __restrict__ wto,
    const float* __restrict__ bo, float* __restrict__ out)
{
    __shared__ __align__(16) unsigned short As[64][72];
    __shared__ __align__(16) unsigned short Bs[64][72];
    const int n0 = blockIdx.x * 64, m0 = blockIdx.y * 64;
    ffrag acc[4];
    gemm64x64(attn, wto, m0, n0, As, Bs, acc);

    const int t  = threadIdx.x;
    const int l  = t & 63, w = t >> 6;
    const int lm = l & 15, lq = l >> 4;
#pragma unroll
    for (int s = 0; s < 4; ++s) {
        const float bb = bo[n0 + s * 16 + lm];
#pragma unroll
        for (int r = 0; r < 4; ++r) {
            const int row = m0 + w * 16 + lq * 4 + r;
            out[(size_t)row * DD + n0 + s * 16 + lm] = acc[s][r] + bb;
        }
    }
}

extern "C" void kernel_launch(void* const* d_in, const int* in_sizes, int n_in,
                              void* d_out, int out_size, void* d_ws, size_t ws_size,
                              hipStream_t stream) {
    const float* x  = (const float*)d_in[0];
    // d_in[1] = causal mask (deterministic triu) — not read
    const float* wq = (const float*)d_in[2];
    const float* bq = (const float*)d_in[3];
    const float* wk = (const float*)d_in[4];
    const float* bk = (const float*)d_in[5];
    const float* wv = (const float*)d_in[6];
    const float* bv = (const float*)d_in[7];
    const float* wo = (const float*)d_in[8];
    const float* bo = (const float*)d_in[9];

    const size_t perT = (size_t)BB * HH * TT * DHH;   // 4,194,304 elems
    const size_t perW = (size_t)DD * DD;              // 1,048,576 elems
    unsigned short* xb   = (unsigned short*)d_ws;     // 4M
    unsigned short* wtq  = xb  + perT;
    unsigned short* wtk  = wtq + perW;
    unsigned short* wtv  = wtk + perW;
    unsigned short* wto  = wtv + perW;
    unsigned short* Qh   = wto + perW;
    unsigned short* Kh   = Qh + perT;
    unsigned short* Vh   = Kh + perT;
    unsigned short* attn = Vh + perT;

    conv_x_kernel<<<(MM * DD / 4) / 256, 256, 0, stream>>>(x, xb);
    transpose_w_kernel<<<dim3(16, 16, 4), 256, 0, stream>>>(
        wq, wk, wv, wo, wtq, wtk, wtv, wto);
    qkv_rope_kernel<<<dim3(16, 64, 3), 256, 0, stream>>>(
        xb, wtq, bq, wtk, bk, wtv, bv, Qh, Kh, Vh);
    attn_kernel<<<dim3(32, 32), 256, 0, stream>>>(Qh, Kh, Vh, attn);
    oproj_kernel<<<dim3(16, 64), 256, 0, stream>>>(attn, wto, bo, (float*)d_out);
}